// Round 1
// baseline (352.994 us; speedup 1.0000x reference)
//
#include <hip/hip_runtime.h>

#define CH    128
#define HH    64
#define WW    96
#define MD    40
#define KD    81
#define HW    (HH*WW)          /* 6144 */
#define CHW   (CH*HW)
#define SCALE 0.08838834764831845f   /* 1/sqrt(128) */
#define LSTR  72               /* ushorts per row: 64 bf16 + 8 pad (16B-aligned rows) */
#define CHUNK (WW*LSTR)        /* 6912 ushorts = 13824 B per (b,y,h) per tensor */
#define WS2_USH ((size_t)2*HH*2*CHUNK)  /* x2 region offset in ushorts */

typedef __attribute__((ext_vector_type(8))) short bf16x8;
typedef __attribute__((ext_vector_type(4))) float f32x4;

__device__ inline unsigned int pack2bf(float lo, float hi) {
    unsigned int a = __float_as_uint(lo), b = __float_as_uint(hi);
    a = (a + 0x7FFFu + ((a >> 16) & 1u)) >> 16;   // RTN bf16
    b = (b + 0x7FFFu + ((b >> 16) & 1u)) >> 16;
    return a | (b << 16);
}

__device__ __forceinline__ void gload16(const void* g, void* l) {
    __builtin_amdgcn_global_load_lds(
        (const __attribute__((address_space(1))) void*)g,
        (__attribute__((address_space(3))) void*)l, 16, 0, 0);
}

// ---------------------------------------------------------------------------
// Pre-pass: transpose+convert x1,x2 rows to bf16 workspace, [b][y][h][x][72].
// Done ONCE per row instead of ~81x inside the correlation blocks.
// ---------------------------------------------------------------------------
__global__ __launch_bounds__(256) void prepack(
    const float* __restrict__ x1, const float* __restrict__ x2,
    unsigned short* __restrict__ ws)
{
    const int y = blockIdx.x;
    const int h = blockIdx.y & 1;
    const int t = blockIdx.y >> 1;
    const int b = blockIdx.z;

    const float* src = (t ? x2 : x1)
        + (size_t)b * CHW + (size_t)(h * 64) * HW + (size_t)y * WW;
    unsigned short* dst = ws + (size_t)t * WS2_USH
        + ((size_t)(b * HH + y) * 2 + h) * CHUNK;

    for (int j = threadIdx.x; j < 8 * WW; j += 256) {   // 3 iters
        const int cg = j / WW;                          // channel octet 0..7
        const int x  = j - cg * WW;
        const float* p = src + (size_t)(cg * 8) * HW + x;
        float f[8];
        #pragma unroll
        for (int i = 0; i < 8; ++i) f[i] = p[(size_t)i * HW];
        uint4 w;
        w.x = pack2bf(f[0], f[1]); w.y = pack2bf(f[2], f[3]);
        w.z = pack2bf(f[4], f[5]); w.w = pack2bf(f[6], f[7]);
        *reinterpret_cast<uint4*>(&dst[(size_t)x * LSTR + cg * 8]) = w;
    }
}

// ---------------------------------------------------------------------------
// Main: one workgroup per (y, dy, b); 256 threads = 4 waves.
// G[x2][x] = sum_c x1[c][x]*x2[c][x2] via 16x16x32 bf16 MFMA; staging is now
// pure global_load_lds from the pre-packed workspace (pad baked in).
// G stored XOR-swizzled: word ^= (row&7)<<2 -> conflict-free G-write AND
// conflict-free diagonal emit read (both verified bank permutations).
// ---------------------------------------------------------------------------
__global__ __launch_bounds__(256, 4) void corr_kernel(
    const unsigned short* __restrict__ ws, float* __restrict__ out)
{
    const int y   = blockIdx.x;
    const int dy  = blockIdx.y;
    const int b   = blockIdx.z;
    const int tid = threadIdx.x;

    float* outbase = out + ((size_t)b * (KD * KD) + (size_t)dy * KD) * HW
                         + (size_t)y * WW;

    const int y2 = y + dy - MD;
    if (y2 < 0 || y2 >= HH) {
        const float4 z = make_float4(0.f, 0.f, 0.f, 0.f);
        for (int f = tid; f < KD * (WW / 4); f += 256) {
            const int dx = f / (WW / 4);
            const int x4 = f - dx * (WW / 4);
            *reinterpret_cast<float4*>(outbase + (size_t)dx * HW + x4 * 4) = z;
        }
        return;
    }

    // Union LDS: staging (2 x 6912 ush = 27648 B) overlapped with
    // G (96x96 fp32 = 36864 B). 36864 B -> 4 blocks/CU.
    __shared__ __align__(16) char smem[WW * WW * 4];
    unsigned short* sStage = reinterpret_cast<unsigned short*>(smem);
    unsigned short* sA = sStage;            // x1 row, [x][c-half]
    unsigned short* sB = sStage + CHUNK;    // x2 row, [x2][c-half]
    float*          sG = reinterpret_cast<float*>(smem);   // G[x2][x] swizzled

    const unsigned short* wsA = ws + ((size_t)(b * HH + y ) * 2) * CHUNK;
    const unsigned short* wsB = ws + WS2_USH + ((size_t)(b * HH + y2) * 2) * CHUNK;

    const int lane = tid & 63;
    const int wave = tid >> 6;
    const int m0   = (wave >> 1) * 48;   // x2-tile base for this wave
    const int n0   = (wave & 1) * 48;    // x-tile base
    const int lr   = lane & 15;
    const int q    = lane >> 4;

    f32x4 acc[3][3];
    #pragma unroll
    for (int i = 0; i < 3; ++i)
        #pragma unroll
        for (int j = 0; j < 3; ++j)
            acc[i][j] = (f32x4){0.f, 0.f, 0.f, 0.f};

    for (int h = 0; h < 2; ++h) {
        if (h) __syncthreads();          // protect half-0 fragment reads
        const unsigned short* g1 = wsA + (size_t)h * CHUNK;
        const unsigned short* g2 = wsB + (size_t)h * CHUNK;
        // Stage both rows: 1728 lane-loads of 16 B, LDS dest linear.
        #pragma unroll
        for (int it = 0; it < 7; ++it) {
            const int idx = it * 256 + tid;
            if (idx < 2 * (CHUNK / 8)) {                 // 1728
                const unsigned short* g = (idx < (CHUNK / 8))
                    ? g1 + (size_t)idx * 8
                    : g2 + (size_t)(idx - (CHUNK / 8)) * 8;
                gload16(g, sStage + (size_t)idx * 8);
            }
        }
        __syncthreads();                 // drains vmcnt before barrier

        #pragma unroll
        for (int kk = 0; kk < 2; ++kk) {
            const int cl = kk * 32 + q * 8;
            bf16x8 af[3], bg[3];
            #pragma unroll
            for (int i = 0; i < 3; ++i)
                af[i] = *reinterpret_cast<const bf16x8*>(&sB[(m0 + 16 * i + lr) * LSTR + cl]);
            #pragma unroll
            for (int j = 0; j < 3; ++j)
                bg[j] = *reinterpret_cast<const bf16x8*>(&sA[(n0 + 16 * j + lr) * LSTR + cl]);
            #pragma unroll
            for (int i = 0; i < 3; ++i)
                #pragma unroll
                for (int j = 0; j < 3; ++j)
                    acc[i][j] = __builtin_amdgcn_mfma_f32_16x16x32_bf16(
                        af[i], bg[j], acc[i][j], 0, 0, 0);
        }
    }

    __syncthreads();                     // all fragment reads done; smem becomes G
    // D layout: col = lane&15 (=x), row = q*4+r (=x2 within tile).
    // XOR-swizzle: word = row*96+col ^ (row&7)<<2. q-groups 0/2 vs 1/3 get
    // XOR values differing by 16 -> two disjoint 16-bank halves -> conflict-free.
    #pragma unroll
    for (int i = 0; i < 3; ++i) {
        #pragma unroll
        for (int j = 0; j < 3; ++j) {
            const int col  = n0 + 16 * j + lr;
            const int rowb = m0 + 16 * i + q * 4;
            #pragma unroll
            for (int r = 0; r < 4; ++r) {
                const int row = rowb + r;
                sG[(row * WW + col) ^ ((row & 7) << 2)] = acc[i][j][r];
            }
        }
    }
    __syncthreads();

    // Emit 81 x 96 slab: out[dx][x] = G[x+dx-40][x] * SCALE (0 outside band).
    // Diagonal read bank = (x%32) ^ 4*((x+dx-40)&7): bijective over x mod 32.
    // Incremental dx/x update replaces per-iter magic-div.
    int dx = tid / WW;                   // 0..2
    int x  = tid - dx * WW;
    #pragma unroll 1
    for (int it = 0; it < 31; ++it) {
        if (dx < KD) {
            const int x2v   = x + dx - MD;
            const bool valid = ((unsigned)x2v < (unsigned)WW);
            const int w     = valid ? ((x2v * WW + x) ^ ((x2v & 7) << 2)) : 0;
            float v = sG[w] * SCALE;
            v = valid ? v : 0.f;
            outbase[(size_t)(dx * HW + x)] = v;
        }
        x += 64; dx += 2;
        if (x >= WW) { x -= WW; ++dx; }
    }
}

extern "C" void kernel_launch(void* const* d_in, const int* in_sizes, int n_in,
                              void* d_out, int out_size, void* d_ws, size_t ws_size,
                              hipStream_t stream) {
    const float* x1 = (const float*)d_in[0];
    const float* x2 = (const float*)d_in[1];
    float* out = (float*)d_out;
    unsigned short* ws = (unsigned short*)d_ws;

    hipLaunchKernelGGL(prepack, dim3(HH, 4, 2), dim3(256), 0, stream, x1, x2, ws);

    dim3 g(HH, KD, 2);   // y, dy, b
    hipLaunchKernelGGL(corr_kernel, g, dim3(256), 0, stream, ws, out);
}